// Round 6
// baseline (932.499 us; speedup 1.0000x reference)
//
#include <hip/hip_runtime.h>

#define NN 100000
#define NE 3200000
#define NBUK 196                  // ceil(NN/512) buckets of 512 nodes
#define CAP 18432                 // max edges per bucket (E/NBUK=16327 + slack)
#define NAB 512                   // binning blocks
#define ECHK ((NE + NAB - 1)/NAB) // 6250 edges per binning block

typedef unsigned short u16;
typedef unsigned int u32;
typedef __attribute__((ext_vector_type(8))) short short8v;
typedef __attribute__((ext_vector_type(4))) float f32x4;

__device__ __forceinline__ u16 f2b(float f){
  u32 u = __float_as_uint(f);
  u32 r = (u + 0x7fffu + ((u >> 16) & 1u)) >> 16;
  return (u16)r;
}
__device__ __forceinline__ float b2f(u16 b){
  return __uint_as_float(((u32)b) << 16);
}

// ---------------- misc: weight transposes (fp32->bf16 NxK) + zero counters -------
__global__ void k_misc(const float* __restrict__ W0, const float* __restrict__ W1,
                       const float* __restrict__ W2, const float* __restrict__ Wm1,
                       u16* __restrict__ wt0, u16* __restrict__ wt1,
                       u16* __restrict__ wt2, u16* __restrict__ wtm1,
                       u32* __restrict__ gcntD, u32* __restrict__ gcntS,
                       float* __restrict__ bns, float* __restrict__ bnq){
  int i = blockIdx.x*256 + threadIdx.x;
  // segments: wt0 16384 | wt1 32768 | wt2 65536 | wtm1 51200 | gcnt 512 | bn 400
  if(i < 16384){
    int n = i >> 7, k = i & 127;                  // K=128,N=128
    wt0[i] = f2b(W0[k*128 + n]);
  } else if((i -= 16384) < 32768){
    int n = i >> 7, k = i & 127;                  // K=128,N=256
    wt1[i] = f2b(W1[k*256 + n]);
  } else if((i -= 32768) < 65536){
    int n = i >> 8, k = i & 255;                  // K=256,N=256
    wt2[i] = f2b(W2[k*256 + n]);
  } else if((i -= 65536) < 51200){
    int n = i >> 8, k = i & 255;                  // K=256,N=200
    wtm1[i] = f2b(Wm1[k*200 + n]);
  } else if((i -= 51200) < 512){
    if(i < 256) gcntD[i] = 0; else gcntS[i-256] = 0;
  } else if((i -= 512) < 400){
    if(i < 200) bns[i] = 0.f; else bnq[i-200] = 0.f;
  }
}

// ---------------- binning: scatter edges into node-range buckets ----------------
__global__ __launch_bounds__(256) void k_bin(const int* __restrict__ src,
                      const int* __restrict__ dst,
                      u32* __restrict__ gcntD, u32* __restrict__ gcntS,
                      u32* __restrict__ pairD, u16* __restrict__ keyS){
  __shared__ u32 cntD[NBUK], cntS[NBUK], offD[NBUK], offS[NBUK];
  int t = threadIdx.x, b = blockIdx.x;
  for(int j=t; j<NBUK; j+=256){ cntD[j]=0; cntS[j]=0; }
  __syncthreads();
  int start = b*ECHK, end = min(start + ECHK, NE);
  for(int e = start + t; e < end; e += 256){
    atomicAdd(&cntD[dst[e] >> 9], 1u);
    atomicAdd(&cntS[src[e] >> 9], 1u);
  }
  __syncthreads();
  for(int j=t; j<NBUK; j+=256){
    offD[j] = atomicAdd(&gcntD[j], cntD[j]);
    offS[j] = atomicAdd(&gcntS[j], cntS[j]);
    cntD[j] = 0; cntS[j] = 0;     // reuse as fill
  }
  __syncthreads();
  for(int e = start + t; e < end; e += 256){
    int d = dst[e], s = src[e];
    int bd = d >> 9, bs = s >> 9;
    u32 pd = offD[bd] + atomicAdd(&cntD[bd], 1u);
    u32 ps = offS[bs] + atomicAdd(&cntS[bs], 1u);
    if(pd < CAP) pairD[bd*CAP + pd] = ((u32)s << 9) | (u32)(d & 511);
    if(ps < CAP) keyS[bs*CAP + ps] = (u16)(s & 511);
  }
}

// ---------------- bucket totals -> bucket edge offsets ----------------
__global__ void k_boff(const u32* __restrict__ gcntD, u32* __restrict__ bOffD){
  if(threadIdx.x==0){
    u32 run = 0;
    for(int i=0;i<NBUK;i++){ bOffD[i]=run; run+=gcntD[i]; }
  }
}

// ---------------- per-dst-bucket: degi, nd, rowp, CSR fill ----------------
__global__ __launch_bounds__(256) void k_bucket_dst(
    const u32* __restrict__ pairD, const u32* __restrict__ gcntD,
    const u32* __restrict__ bOffD, int* __restrict__ degi,
    float* __restrict__ nd, int* __restrict__ rowp, int* __restrict__ csr){
  __shared__ u32 hist[512], excl[512], fill[512], tsum[256];
  int t = threadIdx.x, b = blockIdx.x;
  int base = b << 9;
  hist[t] = 0; hist[t+256] = 0; fill[t] = 0; fill[t+256] = 0;
  __syncthreads();
  int nD = gcntD[b];
  const u32* pp = pairD + (size_t)b*CAP;
  for(int i=t; i<nD; i+=256) atomicAdd(&hist[pp[i] & 511], 1u);
  __syncthreads();
  u32 a0 = hist[2*t], a1 = hist[2*t+1];
  tsum[t] = a0 + a1;
  __syncthreads();
  for(int off=1; off<256; off<<=1){
    u32 v = (t>=off) ? tsum[t-off] : 0;
    __syncthreads();
    tsum[t] += v;
    __syncthreads();
  }
  u32 texc = tsum[t] - (a0 + a1);
  excl[2*t] = texc; excl[2*t+1] = texc + a0;
  __syncthreads();
  u32 bo = bOffD[b];
  #pragma unroll
  for(int j=0;j<2;j++){
    int local = t + j*256;
    int v = base + local;
    if(v < NN){
      int cnt = (int)hist[local];
      degi[v] = cnt + 1;                 // + self-loop
      nd[v] = rsqrtf((float)(cnt + 1));
      rowp[v] = (int)(bo + excl[local]);
    }
  }
  __syncthreads();
  for(int i=t; i<nD; i+=256){
    u32 w = pp[i];
    int local = w & 511;
    u32 pos = bo + excl[local] + atomicAdd(&fill[local], 1u);
    csr[pos] = (int)(w >> 9);
  }
}

// ---------------- per-src-bucket: ns ----------------
__global__ __launch_bounds__(256) void k_bucket_src(
    const u16* __restrict__ keyS, const u32* __restrict__ gcntS,
    float* __restrict__ ns){
  __shared__ u32 hist[512];
  int t = threadIdx.x, b = blockIdx.x;
  hist[t] = 0; hist[t+256] = 0;
  __syncthreads();
  int nS = gcntS[b];
  const u16* kp = keyS + (size_t)b*CAP;
  for(int i=t; i<nS; i+=256) atomicAdd(&hist[kp[i]], 1u);
  __syncthreads();
  #pragma unroll
  for(int j=0;j<2;j++){
    int local = t + j*256;
    int v = (b << 9) + local;
    if(v < NN) ns[v] = rsqrtf((float)(hist[local] + 1));
  }
}

// ---------------- convert features*ns -> bf16 ----------------
__global__ void k_cvt(const float* __restrict__ f, const float* __restrict__ ns,
                      u16* __restrict__ out){
  int i = blockIdx.x*256 + threadIdx.x;    // groups of 4 elems, 32 groups/row
  if(i >= NN*32) return;
  int row = i >> 5;
  float nsv = ns[row];
  float4 v = *(const float4*)(f + (size_t)i*4);
  u32 w0 = (u32)f2b(v.x*nsv) | ((u32)f2b(v.y*nsv) << 16);
  u32 w1 = (u32)f2b(v.z*nsv) | ((u32)f2b(v.w*nsv) << 16);
  *(uint2*)(out + (size_t)i*4) = make_uint2(w0, w1);
}

// ---------------- SpMM: EP=16 edge-groups of 4 lanes, optional col-split --------
// h: bf16 rows premultiplied by norm_src. out: bf16 rows * norm_dst.
// SPLIT=2: two waves per node, each handles 128 contiguous columns.
template<int DIM, int SPLIT>
__global__ void k_spmm16(const u16* __restrict__ h, const int* __restrict__ rowp,
                         const int* __restrict__ degi, const int* __restrict__ csr,
                         const float* __restrict__ nd, u16* __restrict__ out){
  constexpr int D2 = DIM/SPLIT;      // 128 columns per wave
  constexpr int EP = 16, G = 4;
  constexpr int NV = D2/(G*8);       // 4 uint4 per lane
  int wg = (blockIdx.x*blockDim.x + threadIdx.x) >> 6;
  int lane = threadIdx.x & 63;
  int node, co;                       // co = column offset in uint4 units
  if(SPLIT == 2){ node = wg >> 1; co = (wg & 1)*(D2/8); }
  else          { node = wg;      co = 0; }
  if(node >= NN) return;
  int g = lane >> 2, gl = lane & 3;
  const uint4* hv = (const uint4*)h;  // DIM/8 uint4 per row
  float acc[NV*8];
  #pragma unroll
  for(int i=0;i<NV*8;i++) acc[i]=0.f;

  auto addrow = [&](int n){
    #pragma unroll
    for(int v4=0; v4<NV; v4++){
      uint4 v = hv[(size_t)n*(DIM/8) + co + gl*NV + v4];
      u32 wd[4] = {v.x, v.y, v.z, v.w};
      #pragma unroll
      for(int i=0;i<4;i++){
        acc[v4*8 + 2*i]   += b2f((u16)(wd[i] & 0xffff));
        acc[v4*8 + 2*i+1] += b2f((u16)(wd[i] >> 16));
      }
    }
  };

  if(g == 0) addrow(node);            // self-loop term
  int start = rowp[node];
  int cnt = degi[node]-1;
  for(int j=g; j<cnt; j+=EP) addrow(csr[start+j]);

  // combine 16 edge-groups (4-lane stride)
  #pragma unroll
  for(int i=0;i<NV*8;i++){
    acc[i] += __shfl_xor(acc[i], 4);
    acc[i] += __shfl_xor(acc[i], 8);
    acc[i] += __shfl_xor(acc[i], 16);
    acc[i] += __shfl_xor(acc[i], 32);
  }
  if(g == 0){
    float ndv = nd[node];
    #pragma unroll
    for(int v4=0; v4<NV; v4++){
      u32 o[4];
      #pragma unroll
      for(int i=0;i<4;i++){
        o[i] = (u32)f2b(acc[v4*8+2*i]*ndv) | ((u32)f2b(acc[v4*8+2*i+1]*ndv) << 16);
      }
      *(uint4*)(out + (size_t)node*DIM + (co + gl*NV + v4)*8) = make_uint4(o[0],o[1],o[2],o[3]);
    }
  }
}

// ---------------- bf16 MFMA GEMM: out = relu(A @ Wt^T + bias) ----------------
// OUTMODE 0: bf16 out * ns[row]; 1: bf16 out; 2: fp32 out + BN col sums.
template<int OUTMODE>
__global__ __launch_bounds__(256) void k_gemm_mfma(
    const u16* __restrict__ A, const u16* __restrict__ Bt,
    const float* __restrict__ bias, const float* __restrict__ ns,
    u16* __restrict__ outb, float* __restrict__ outf,
    float* __restrict__ bns, float* __restrict__ bnq,
    int M, int K, int Nn)
{
  __shared__ u16 As[128*32];
  __shared__ u16 Bs[128*32];
  int t = threadIdx.x;
  int wave = t >> 6, lane = t & 63;
  int l15 = lane & 15, l4 = lane >> 4;
  int wr = (wave >> 1)*64, wc = (wave & 1)*64;
  int row0 = blockIdx.y*128, col0 = blockIdx.x*128;

  f32x4 acc[4][4];
  #pragma unroll
  for(int m=0;m<4;m++)
    #pragma unroll
    for(int n=0;n<4;n++) acc[m][n] = (f32x4)(0.f);

  int st_r = t >> 1;
  int kc0 = (t & 1)*2;
  int sw  = (st_r >> 1) & 3;
  int c0 = kc0 ^ sw, c1 = (kc0+1) ^ sw;
  bool avalid = (row0 + st_r) < M;
  bool bvalid = (col0 + st_r) < Nn;
  const u16* Ap = A  + (size_t)(row0 + st_r)*K + kc0*8;
  const u16* Bp = Bt + (size_t)(col0 + st_r)*K + kc0*8;

  for(int k0 = 0; k0 < K; k0 += 32){
    uint4 va0 = make_uint4(0,0,0,0), va1 = va0, vb0 = va0, vb1 = va0;
    if(avalid){ va0 = *(const uint4*)(Ap + k0); va1 = *(const uint4*)(Ap + k0 + 8); }
    if(bvalid){ vb0 = *(const uint4*)(Bp + k0); vb1 = *(const uint4*)(Bp + k0 + 8); }
    __syncthreads();
    *(uint4*)&As[st_r*32 + c0*8] = va0;
    *(uint4*)&As[st_r*32 + c1*8] = va1;
    *(uint4*)&Bs[st_r*32 + c0*8] = vb0;
    *(uint4*)&Bs[st_r*32 + c1*8] = vb1;
    __syncthreads();

    short8v af[4], bg[4];
    #pragma unroll
    for(int m=0;m<4;m++){
      int r = wr + m*16 + l15;
      int kc = l4 ^ ((r >> 1) & 3);
      af[m] = *(const short8v*)&As[r*32 + kc*8];
    }
    #pragma unroll
    for(int n=0;n<4;n++){
      int r = wc + n*16 + l15;
      int kc = l4 ^ ((r >> 1) & 3);
      bg[n] = *(const short8v*)&Bs[r*32 + kc*8];
    }
    #pragma unroll
    for(int m=0;m<4;m++)
      #pragma unroll
      for(int n=0;n<4;n++)
        acc[m][n] = __builtin_amdgcn_mfma_f32_16x16x32_bf16(af[m], bg[n], acc[m][n], 0, 0, 0);
    __syncthreads();
  }

  float nsv[4][4];
  if(OUTMODE == 0){
    #pragma unroll
    for(int m=0;m<4;m++)
      #pragma unroll
      for(int r=0;r<4;r++){
        int gr = row0 + wr + m*16 + l4*4 + r;
        nsv[m][r] = (gr < M) ? ns[gr] : 0.f;
      }
  }
  #pragma unroll
  for(int n=0;n<4;n++){
    int gc = col0 + wc + n*16 + l15;
    float bv = (gc < Nn) ? bias[gc] : 0.f;
    float s = 0.f, q = 0.f;
    #pragma unroll
    for(int m=0;m<4;m++){
      #pragma unroll
      for(int r=0;r<4;r++){
        int gr = row0 + wr + m*16 + l4*4 + r;
        bool ok = (gr < M) && (gc < Nn);
        float v = ok ? fmaxf(acc[m][n][r] + bv, 0.f) : 0.f;
        if(ok){
          if(OUTMODE == 0)      outb[(size_t)gr*Nn + gc] = f2b(v * nsv[m][r]);
          else if(OUTMODE == 1) outb[(size_t)gr*Nn + gc] = f2b(v);
          else                  outf[(size_t)gr*Nn + gc] = v;
        }
        if(OUTMODE == 2){ s += v; q += v*v; }
      }
    }
    if(OUTMODE == 2){
      s += __shfl_xor(s, 16); s += __shfl_xor(s, 32);
      q += __shfl_xor(q, 16); q += __shfl_xor(q, 32);
      if(l4 == 0 && gc < Nn){ atomicAdd(&bns[gc], s); atomicAdd(&bnq[gc], q); }
    }
  }
}

// ---------------- batchnorm finalize + fused final linear ----------------
__global__ void k_bn2(const float* __restrict__ bns, const float* __restrict__ bnq,
                      const float* __restrict__ gamma, const float* __restrict__ beta,
                      const float* __restrict__ Wm2, const float* __restrict__ bm2,
                      float* __restrict__ w2a, float* __restrict__ cc2){
  __shared__ float c0s[200];
  int t = threadIdx.x;
  if(t<200){
    float mu  = bns[t] * (1.0f/NN);
    float var = bnq[t] * (1.0f/NN) - mu*mu;
    float a   = rsqrtf(var + 1e-5f) * gamma[t];
    w2a[t*2+0] = a*Wm2[t*2+0];
    w2a[t*2+1] = a*Wm2[t*2+1];
    c0s[t] = beta[t] - mu*a;
  }
  __syncthreads();
  if(t<2){
    float cst = bm2[t];
    for(int k=0;k<200;k++) cst += c0s[k]*Wm2[k*2+t];
    cc2[t] = cst;
  }
}

__global__ void k_final(const float* __restrict__ z, const float* __restrict__ w2a,
                        const float* __restrict__ cc2, float* __restrict__ out){
  int lane = threadIdx.x & 63;
  int gw = (blockIdx.x*blockDim.x + threadIdx.x) >> 6;
  if(gw >= NN) return;
  const float* zr = z + (size_t)gw*200;
  float p0=0.f, p1=0.f;
  #pragma unroll
  for(int i=0;i<4;i++){
    int c = lane + i*64;
    if(c<200){ float x=zr[c]; p0 += x*w2a[c*2+0]; p1 += x*w2a[c*2+1]; }
  }
  for(int off=32; off>0; off>>=1){
    p0 += __shfl_down(p0, off);
    p1 += __shfl_down(p1, off);
  }
  if(lane==0){ out[gw*2+0] = p0 + cc2[0]; out[gw*2+1] = p1 + cc2[1]; }
}

// ---------------- launch ----------------
extern "C" void kernel_launch(void* const* d_in, const int* in_sizes, int n_in,
                              void* d_out, int out_size, void* d_ws, size_t ws_size,
                              hipStream_t stream) {
  const float* features = (const float*)d_in[0];
  const int*   src = (const int*)d_in[1];
  const int*   dst = (const int*)d_in[2];
  const float* W0  = (const float*)d_in[3];
  const float* b0  = (const float*)d_in[4];
  const float* W1  = (const float*)d_in[5];
  const float* b1  = (const float*)d_in[6];
  const float* W2  = (const float*)d_in[7];
  const float* b2  = (const float*)d_in[8];
  const float* Wm1 = (const float*)d_in[9];
  const float* bm1 = (const float*)d_in[10];
  const float* gamma = (const float*)d_in[11];
  const float* beta  = (const float*)d_in[12];
  const float* Wm2 = (const float*)d_in[13];
  const float* bm2 = (const float*)d_in[14];
  float* out = (float*)d_out;

  char* p = (char*)d_ws;
  auto alloc = [&](size_t bytes)->void*{
    void* r = (void*)p; p += (bytes + 255) & ~(size_t)255; return r;
  };
  u16*   X    = (u16*)alloc((size_t)NN*256*2);
  u16*   Y    = (u16*)alloc((size_t)NN*256*2);
  float* z    = (float*)alloc((size_t)NN*200*4);     // 80 MB, dead until MLP GEMM
  int*   csr  = (int*)alloc((size_t)NE*4);
  int*   rowp = (int*)alloc((size_t)NN*4);
  int*   degi = (int*)alloc((size_t)NN*4);
  float* ns   = (float*)alloc((size_t)NN*4);
  float* nd   = (float*)alloc((size_t)NN*4);
  u32*   gcntD = (u32*)alloc(256*4);
  u32*   gcntS = (u32*)alloc(256*4);
  u32*   bOffD = (u32*)alloc(256*4);
  float* bns  = (float*)alloc(200*4);
  float* bnq  = (float*)alloc(200*4);
  float* w2a  = (float*)alloc(400*4);
  float* cc2  = (float*)alloc(2*4);
  u16*   wt0  = (u16*)alloc((size_t)128*128*2);
  u16*   wt1  = (u16*)alloc((size_t)256*128*2);
  u16*   wt2  = (u16*)alloc((size_t)256*256*2);
  u16*   wtm1 = (u16*)alloc((size_t)200*256*2);
  // bucket scratch aliased onto z (lifetimes disjoint): pairD 14.5MB, keyS 7.3MB
  u32*   pairD = (u32*)z;
  u16*   keyS  = (u16*)((char*)z + (size_t)32*1024*1024);

  // prep: transposes + zero counters, then binned counting sort
  k_misc<<<(16384+32768+65536+51200+512+400 + 255)/256, 256, 0, stream>>>(
      W0, W1, W2, Wm1, wt0, wt1, wt2, wtm1, gcntD, gcntS, bns, bnq);
  k_bin<<<NAB, 256, 0, stream>>>(src, dst, gcntD, gcntS, pairD, keyS);
  k_boff<<<1, 64, 0, stream>>>(gcntD, bOffD);
  k_bucket_dst<<<NBUK, 256, 0, stream>>>(pairD, gcntD, bOffD, degi, nd, rowp, csr);
  k_bucket_src<<<NBUK, 256, 0, stream>>>(keyS, gcntS, ns);

  // features * ns -> bf16
  k_cvt<<<(NN*32 + 255)/256, 256, 0, stream>>>(features, ns, X);

  int sblk1 = (NN + 3)/4;            // 1 wave per node
  int sblk2 = (2*NN + 3)/4;          // 2 waves per node (col-split)
  int gblk = (NN + 127)/128;         // GEMM row blocks

  // layer 0
  k_spmm16<128,1><<<sblk1, 256, 0, stream>>>(X, rowp, degi, csr, nd, Y);
  k_gemm_mfma<0><<<dim3(1,gblk), 256, 0, stream>>>(Y, wt0, b0, ns, X, nullptr, nullptr, nullptr, NN, 128, 128);
  // layer 1
  k_spmm16<128,1><<<sblk1, 256, 0, stream>>>(X, rowp, degi, csr, nd, Y);
  k_gemm_mfma<0><<<dim3(2,gblk), 256, 0, stream>>>(Y, wt1, b1, ns, X, nullptr, nullptr, nullptr, NN, 128, 256);
  // layer 2
  k_spmm16<256,2><<<sblk2, 256, 0, stream>>>(X, rowp, degi, csr, nd, Y);
  k_gemm_mfma<1><<<dim3(2,gblk), 256, 0, stream>>>(Y, wt2, b2, nullptr, X, nullptr, nullptr, nullptr, NN, 256, 256);
  // MLP hidden: z = relu(h3 @ Wm1 + bm1) + fused BN column stats
  k_gemm_mfma<2><<<dim3(2,gblk), 256, 0, stream>>>(X, wtm1, bm1, nullptr, nullptr, z, bns, bnq, NN, 256, 200);

  // batchnorm finalize + final linear
  k_bn2<<<1, 256, 0, stream>>>(bns, bnq, gamma, beta, Wm2, bm2, w2a, cc2);
  k_final<<<sblk1, 256, 0, stream>>>(z, w2a, cc2, out);
}

// Round 7
// 806.549 us; speedup vs baseline: 1.1562x; 1.1562x over previous
//
#include <hip/hip_runtime.h>

#define NN 100000
#define NE 3200000
#define NBUK 196                  // ceil(NN/512) buckets of 512 nodes
#define CAP 18432                 // max edges per bucket (E/NBUK=16327 + slack)
#define NAB 512                   // binning blocks
#define ECHK ((NE + NAB - 1)/NAB) // 6250 edges per binning block

typedef unsigned short u16;
typedef unsigned int u32;
typedef __attribute__((ext_vector_type(8))) short short8v;
typedef __attribute__((ext_vector_type(4))) float f32x4;

__device__ __forceinline__ u16 f2b(float f){
  u32 u = __float_as_uint(f);
  u32 r = (u + 0x7fffu + ((u >> 16) & 1u)) >> 16;
  return (u16)r;
}
__device__ __forceinline__ float b2f(u16 b){
  return __uint_as_float(((u32)b) << 16);
}

// ---------------- misc: weight transposes (fp32->bf16 NxK) + zero counters -------
__global__ void k_misc(const float* __restrict__ W0, const float* __restrict__ W1,
                       const float* __restrict__ W2, const float* __restrict__ Wm1,
                       u16* __restrict__ wt0, u16* __restrict__ wt1,
                       u16* __restrict__ wt2, u16* __restrict__ wtm1,
                       u32* __restrict__ gcntD, u32* __restrict__ gcntS,
                       float* __restrict__ bns, float* __restrict__ bnq){
  int i = blockIdx.x*256 + threadIdx.x;
  if(i < 16384){
    int n = i >> 7, k = i & 127;                  // K=128,N=128
    wt0[i] = f2b(W0[k*128 + n]);
  } else if((i -= 16384) < 32768){
    int n = i >> 7, k = i & 127;                  // K=128,N=256
    wt1[i] = f2b(W1[k*256 + n]);
  } else if((i -= 32768) < 65536){
    int n = i >> 8, k = i & 255;                  // K=256,N=256
    wt2[i] = f2b(W2[k*256 + n]);
  } else if((i -= 65536) < 51200){
    int n = i >> 8, k = i & 255;                  // K=256,N=200
    wtm1[i] = f2b(Wm1[k*200 + n]);
  } else if((i -= 51200) < 512){
    if(i < 256) gcntD[i] = 0; else gcntS[i-256] = 0;
  } else if((i -= 512) < 400){
    if(i < 200) bns[i] = 0.f; else bnq[i-200] = 0.f;
  }
}

// ---------------- binning: scatter edges into node-range buckets ----------------
__global__ __launch_bounds__(256) void k_bin(const int* __restrict__ src,
                      const int* __restrict__ dst,
                      u32* __restrict__ gcntD, u32* __restrict__ gcntS,
                      u32* __restrict__ pairD, u16* __restrict__ keyS){
  __shared__ u32 cntD[NBUK], cntS[NBUK], offD[NBUK], offS[NBUK];
  int t = threadIdx.x, b = blockIdx.x;
  for(int j=t; j<NBUK; j+=256){ cntD[j]=0; cntS[j]=0; }
  __syncthreads();
  int start = b*ECHK, end = min(start + ECHK, NE);
  for(int e = start + t; e < end; e += 256){
    atomicAdd(&cntD[dst[e] >> 9], 1u);
    atomicAdd(&cntS[src[e] >> 9], 1u);
  }
  __syncthreads();
  for(int j=t; j<NBUK; j+=256){
    offD[j] = atomicAdd(&gcntD[j], cntD[j]);
    offS[j] = atomicAdd(&gcntS[j], cntS[j]);
    cntD[j] = 0; cntS[j] = 0;     // reuse as fill
  }
  __syncthreads();
  for(int e = start + t; e < end; e += 256){
    int d = dst[e], s = src[e];
    int bd = d >> 9, bs = s >> 9;
    u32 pd = offD[bd] + atomicAdd(&cntD[bd], 1u);
    u32 ps = offS[bs] + atomicAdd(&cntS[bs], 1u);
    if(pd < CAP) pairD[bd*CAP + pd] = ((u32)s << 9) | (u32)(d & 511);
    if(ps < CAP) keyS[bs*CAP + ps] = (u16)(s & 511);
  }
}

// ---------------- bucket totals -> bucket edge offsets ----------------
__global__ void k_boff(const u32* __restrict__ gcntD, u32* __restrict__ bOffD){
  if(threadIdx.x==0){
    u32 run = 0;
    for(int i=0;i<NBUK;i++){ bOffD[i]=run; run+=gcntD[i]; }
  }
}

// ---------------- per-dst-bucket: degi, nd, rowp, CSR fill ----------------
__global__ __launch_bounds__(256) void k_bucket_dst(
    const u32* __restrict__ pairD, const u32* __restrict__ gcntD,
    const u32* __restrict__ bOffD, int* __restrict__ degi,
    float* __restrict__ nd, int* __restrict__ rowp, int* __restrict__ csr){
  __shared__ u32 hist[512], excl[512], fill[512], tsum[256];
  int t = threadIdx.x, b = blockIdx.x;
  int base = b << 9;
  hist[t] = 0; hist[t+256] = 0; fill[t] = 0; fill[t+256] = 0;
  __syncthreads();
  int nD = gcntD[b];
  const u32* pp = pairD + (size_t)b*CAP;
  for(int i=t; i<nD; i+=256) atomicAdd(&hist[pp[i] & 511], 1u);
  __syncthreads();
  u32 a0 = hist[2*t], a1 = hist[2*t+1];
  tsum[t] = a0 + a1;
  __syncthreads();
  for(int off=1; off<256; off<<=1){
    u32 v = (t>=off) ? tsum[t-off] : 0;
    __syncthreads();
    tsum[t] += v;
    __syncthreads();
  }
  u32 texc = tsum[t] - (a0 + a1);
  excl[2*t] = texc; excl[2*t+1] = texc + a0;
  __syncthreads();
  u32 bo = bOffD[b];
  #pragma unroll
  for(int j=0;j<2;j++){
    int local = t + j*256;
    int v = base + local;
    if(v < NN){
      int cnt = (int)hist[local];
      degi[v] = cnt + 1;                 // + self-loop
      nd[v] = rsqrtf((float)(cnt + 1));
      rowp[v] = (int)(bo + excl[local]);
    }
  }
  __syncthreads();
  for(int i=t; i<nD; i+=256){
    u32 w = pp[i];
    int local = w & 511;
    u32 pos = bo + excl[local] + atomicAdd(&fill[local], 1u);
    csr[pos] = (int)(w >> 9);
  }
}

// ---------------- per-src-bucket: ns ----------------
__global__ __launch_bounds__(256) void k_bucket_src(
    const u16* __restrict__ keyS, const u32* __restrict__ gcntS,
    float* __restrict__ ns){
  __shared__ u32 hist[512];
  int t = threadIdx.x, b = blockIdx.x;
  hist[t] = 0; hist[t+256] = 0;
  __syncthreads();
  int nS = gcntS[b];
  const u16* kp = keyS + (size_t)b*CAP;
  for(int i=t; i<nS; i+=256) atomicAdd(&hist[kp[i]], 1u);
  __syncthreads();
  #pragma unroll
  for(int j=0;j<2;j++){
    int local = t + j*256;
    int v = (b << 9) + local;
    if(v < NN) ns[v] = rsqrtf((float)(hist[local] + 1));
  }
}

// ---------------- convert features*ns -> bf16 ----------------
__global__ void k_cvt(const float* __restrict__ f, const float* __restrict__ ns,
                      u16* __restrict__ out){
  int i = blockIdx.x*256 + threadIdx.x;    // groups of 4 elems, 32 groups/row
  if(i >= NN*32) return;
  int row = i >> 5;
  float nsv = ns[row];
  float4 v = *(const float4*)(f + (size_t)i*4);
  u32 w0 = (u32)f2b(v.x*nsv) | ((u32)f2b(v.y*nsv) << 16);
  u32 w1 = (u32)f2b(v.z*nsv) | ((u32)f2b(v.w*nsv) << 16);
  *(uint2*)(out + (size_t)i*4) = make_uint2(w0, w1);
}

// ---------------- SpMM: EP=8 groups of 8 lanes, register double-buffer ----------
// h: bf16 rows premultiplied by norm_src. out: bf16 rows * norm_dst.
// Virtual edge list = [self] ++ csr[rowp .. rowp+cnt); group g takes k = g, g+8, ...
template<int DIM>
__global__ void k_spmm8(const u16* __restrict__ h, const int* __restrict__ rowp,
                        const int* __restrict__ degi, const int* __restrict__ csr,
                        const float* __restrict__ nd, u16* __restrict__ out){
  constexpr int EP = 8, G = 8;
  constexpr int NV = DIM/(G*8);      // uint4 per lane per row (2 or 4)
  int w = (blockIdx.x*blockDim.x + threadIdx.x) >> 6;
  int lane = threadIdx.x & 63;
  if(w >= NN) return;
  int g = lane >> 3, gl = lane & 7;
  const uint4* hv = (const uint4*)h;  // DIM/8 uint4 per row
  float acc[NV*8];
  #pragma unroll
  for(int i=0;i<NV*8;i++) acc[i]=0.f;

  int start = rowp[w];
  int vcnt = degi[w];                 // cnt + 1 (self first)

  uint4 cur[NV];
  int k = g;
  if(k < vcnt){
    int n0 = (k == 0) ? w : csr[start + k - 1];
    #pragma unroll
    for(int v4=0; v4<NV; v4++) cur[v4] = hv[(size_t)n0*(DIM/8) + gl*NV + v4];

    int kn = k + EP;
    int nn = (kn < vcnt) ? csr[start + kn - 1] : 0;   // csr prefetch

    while(true){
      bool more = (kn < vcnt);
      uint4 nxt[NV];
      if(more){
        #pragma unroll
        for(int v4=0; v4<NV; v4++) nxt[v4] = hv[(size_t)nn*(DIM/8) + gl*NV + v4];
      }
      int k2 = kn + EP;
      if(k2 < vcnt) nn = csr[start + k2 - 1];          // csr prefetch 2 ahead
      // accumulate cur (covers nxt load latency)
      #pragma unroll
      for(int v4=0; v4<NV; v4++){
        u32 wd[4] = {cur[v4].x, cur[v4].y, cur[v4].z, cur[v4].w};
        #pragma unroll
        for(int i=0;i<4;i++){
          acc[v4*8 + 2*i]   += __uint_as_float(wd[i] << 16);
          acc[v4*8 + 2*i+1] += __uint_as_float(wd[i] & 0xffff0000u);
        }
      }
      if(!more) break;
      #pragma unroll
      for(int v4=0; v4<NV; v4++) cur[v4] = nxt[v4];
      kn = k2;
    }
  }

  // combine 8 edge-groups (8-lane stride)
  #pragma unroll
  for(int i=0;i<NV*8;i++){
    acc[i] += __shfl_xor(acc[i], 8);
    acc[i] += __shfl_xor(acc[i], 16);
    acc[i] += __shfl_xor(acc[i], 32);
  }
  if(g == 0){
    float ndv = nd[w];
    #pragma unroll
    for(int v4=0; v4<NV; v4++){
      u32 o[4];
      #pragma unroll
      for(int i=0;i<4;i++){
        o[i] = (u32)f2b(acc[v4*8+2*i]*ndv) | ((u32)f2b(acc[v4*8+2*i+1]*ndv) << 16);
      }
      *(uint4*)(out + (size_t)w*DIM + (gl*NV + v4)*8) = make_uint4(o[0],o[1],o[2],o[3]);
    }
  }
}

// ---------------- bf16 MFMA GEMM: out = relu(A @ Wt^T + bias) ----------------
// OUTMODE 0: bf16 out * ns[row]; 1: bf16 out; 2: fp32 out + BN col sums.
template<int OUTMODE>
__global__ __launch_bounds__(256) void k_gemm_mfma(
    const u16* __restrict__ A, const u16* __restrict__ Bt,
    const float* __restrict__ bias, const float* __restrict__ ns,
    u16* __restrict__ outb, float* __restrict__ outf,
    float* __restrict__ bns, float* __restrict__ bnq,
    int M, int K, int Nn)
{
  __shared__ u16 As[128*32];
  __shared__ u16 Bs[128*32];
  int t = threadIdx.x;
  int wave = t >> 6, lane = t & 63;
  int l15 = lane & 15, l4 = lane >> 4;
  int wr = (wave >> 1)*64, wc = (wave & 1)*64;
  int row0 = blockIdx.y*128, col0 = blockIdx.x*128;

  f32x4 acc[4][4];
  #pragma unroll
  for(int m=0;m<4;m++)
    #pragma unroll
    for(int n=0;n<4;n++) acc[m][n] = (f32x4)(0.f);

  int st_r = t >> 1;
  int kc0 = (t & 1)*2;
  int sw  = (st_r >> 1) & 3;
  int c0 = kc0 ^ sw, c1 = (kc0+1) ^ sw;
  bool avalid = (row0 + st_r) < M;
  bool bvalid = (col0 + st_r) < Nn;
  const u16* Ap = A  + (size_t)(row0 + st_r)*K + kc0*8;
  const u16* Bp = Bt + (size_t)(col0 + st_r)*K + kc0*8;

  for(int k0 = 0; k0 < K; k0 += 32){
    uint4 va0 = make_uint4(0,0,0,0), va1 = va0, vb0 = va0, vb1 = va0;
    if(avalid){ va0 = *(const uint4*)(Ap + k0); va1 = *(const uint4*)(Ap + k0 + 8); }
    if(bvalid){ vb0 = *(const uint4*)(Bp + k0); vb1 = *(const uint4*)(Bp + k0 + 8); }
    __syncthreads();
    *(uint4*)&As[st_r*32 + c0*8] = va0;
    *(uint4*)&As[st_r*32 + c1*8] = va1;
    *(uint4*)&Bs[st_r*32 + c0*8] = vb0;
    *(uint4*)&Bs[st_r*32 + c1*8] = vb1;
    __syncthreads();

    short8v af[4], bg[4];
    #pragma unroll
    for(int m=0;m<4;m++){
      int r = wr + m*16 + l15;
      int kc = l4 ^ ((r >> 1) & 3);
      af[m] = *(const short8v*)&As[r*32 + kc*8];
    }
    #pragma unroll
    for(int n=0;n<4;n++){
      int r = wc + n*16 + l15;
      int kc = l4 ^ ((r >> 1) & 3);
      bg[n] = *(const short8v*)&Bs[r*32 + kc*8];
    }
    #pragma unroll
    for(int m=0;m<4;m++)
      #pragma unroll
      for(int n=0;n<4;n++)
        acc[m][n] = __builtin_amdgcn_mfma_f32_16x16x32_bf16(af[m], bg[n], acc[m][n], 0, 0, 0);
    __syncthreads();
  }

  float nsv[4][4];
  if(OUTMODE == 0){
    #pragma unroll
    for(int m=0;m<4;m++)
      #pragma unroll
      for(int r=0;r<4;r++){
        int gr = row0 + wr + m*16 + l4*4 + r;
        nsv[m][r] = (gr < M) ? ns[gr] : 0.f;
      }
  }
  #pragma unroll
  for(int n=0;n<4;n++){
    int gc = col0 + wc + n*16 + l15;
    float bv = (gc < Nn) ? bias[gc] : 0.f;
    float s = 0.f, q = 0.f;
    #pragma unroll
    for(int m=0;m<4;m++){
      #pragma unroll
      for(int r=0;r<4;r++){
        int gr = row0 + wr + m*16 + l4*4 + r;
        bool ok = (gr < M) && (gc < Nn);
        float v = ok ? fmaxf(acc[m][n][r] + bv, 0.f) : 0.f;
        if(ok){
          if(OUTMODE == 0)      outb[(size_t)gr*Nn + gc] = f2b(v * nsv[m][r]);
          else if(OUTMODE == 1) outb[(size_t)gr*Nn + gc] = f2b(v);
          else                  outf[(size_t)gr*Nn + gc] = v;
        }
        if(OUTMODE == 2){ s += v; q += v*v; }
      }
    }
    if(OUTMODE == 2){
      s += __shfl_xor(s, 16); s += __shfl_xor(s, 32);
      q += __shfl_xor(q, 16); q += __shfl_xor(q, 32);
      if(l4 == 0 && gc < Nn){ atomicAdd(&bns[gc], s); atomicAdd(&bnq[gc], q); }
    }
  }
}

// ---------------- batchnorm finalize + fused final linear ----------------
__global__ void k_bn2(const float* __restrict__ bns, const float* __restrict__ bnq,
                      const float* __restrict__ gamma, const float* __restrict__ beta,
                      const float* __restrict__ Wm2, const float* __restrict__ bm2,
                      float* __restrict__ w2a, float* __restrict__ cc2){
  __shared__ float c0s[200];
  int t = threadIdx.x;
  if(t<200){
    float mu  = bns[t] * (1.0f/NN);
    float var = bnq[t] * (1.0f/NN) - mu*mu;
    float a   = rsqrtf(var + 1e-5f) * gamma[t];
    w2a[t*2+0] = a*Wm2[t*2+0];
    w2a[t*2+1] = a*Wm2[t*2+1];
    c0s[t] = beta[t] - mu*a;
  }
  __syncthreads();
  if(t<2){
    float cst = bm2[t];
    for(int k=0;k<200;k++) cst += c0s[k]*Wm2[k*2+t];
    cc2[t] = cst;
  }
}

__global__ void k_final(const float* __restrict__ z, const float* __restrict__ w2a,
                        const float* __restrict__ cc2, float* __restrict__ out){
  int lane = threadIdx.x & 63;
  int gw = (blockIdx.x*blockDim.x + threadIdx.x) >> 6;
  if(gw >= NN) return;
  const float* zr = z + (size_t)gw*200;
  float p0=0.f, p1=0.f;
  #pragma unroll
  for(int i=0;i<4;i++){
    int c = lane + i*64;
    if(c<200){ float x=zr[c]; p0 += x*w2a[c*2+0]; p1 += x*w2a[c*2+1]; }
  }
  for(int off=32; off>0; off>>=1){
    p0 += __shfl_down(p0, off);
    p1 += __shfl_down(p1, off);
  }
  if(lane==0){ out[gw*2+0] = p0 + cc2[0]; out[gw*2+1] = p1 + cc2[1]; }
}

// ---------------- launch ----------------
extern "C" void kernel_launch(void* const* d_in, const int* in_sizes, int n_in,
                              void* d_out, int out_size, void* d_ws, size_t ws_size,
                              hipStream_t stream) {
  const float* features = (const float*)d_in[0];
  const int*   src = (const int*)d_in[1];
  const int*   dst = (const int*)d_in[2];
  const float* W0  = (const float*)d_in[3];
  const float* b0  = (const float*)d_in[4];
  const float* W1  = (const float*)d_in[5];
  const float* b1  = (const float*)d_in[6];
  const float* W2  = (const float*)d_in[7];
  const float* b2  = (const float*)d_in[8];
  const float* Wm1 = (const float*)d_in[9];
  const float* bm1 = (const float*)d_in[10];
  const float* gamma = (const float*)d_in[11];
  const float* beta  = (const float*)d_in[12];
  const float* Wm2 = (const float*)d_in[13];
  const float* bm2 = (const float*)d_in[14];
  float* out = (float*)d_out;

  char* p = (char*)d_ws;
  auto alloc = [&](size_t bytes)->void*{
    void* r = (void*)p; p += (bytes + 255) & ~(size_t)255; return r;
  };
  u16*   X    = (u16*)alloc((size_t)NN*256*2);
  u16*   Y    = (u16*)alloc((size_t)NN*256*2);
  float* z    = (float*)alloc((size_t)NN*200*4);     // 80 MB, dead until MLP GEMM
  int*   csr  = (int*)alloc((size_t)NE*4);
  int*   rowp = (int*)alloc((size_t)NN*4);
  int*   degi = (int*)alloc((size_t)NN*4);
  float* ns   = (float*)alloc((size_t)NN*4);
  float* nd   = (float*)alloc((size_t)NN*4);
  u32*   gcntD = (u32*)alloc(256*4);
  u32*   gcntS = (u32*)alloc(256*4);
  u32*   bOffD = (u32*)alloc(256*4);
  float* bns  = (float*)alloc(200*4);
  float* bnq  = (float*)alloc(200*4);
  float* w2a  = (float*)alloc(400*4);
  float* cc2  = (float*)alloc(2*4);
  u16*   wt0  = (u16*)alloc((size_t)128*128*2);
  u16*   wt1  = (u16*)alloc((size_t)256*128*2);
  u16*   wt2  = (u16*)alloc((size_t)256*256*2);
  u16*   wtm1 = (u16*)alloc((size_t)200*256*2);
  // bucket scratch aliased onto z (lifetimes disjoint): pairD 14.5MB, keyS 7.3MB
  u32*   pairD = (u32*)z;
  u16*   keyS  = (u16*)((char*)z + (size_t)32*1024*1024);

  // prep: transposes + zero counters, then binned counting sort
  k_misc<<<(16384+32768+65536+51200+512+400 + 255)/256, 256, 0, stream>>>(
      W0, W1, W2, Wm1, wt0, wt1, wt2, wtm1, gcntD, gcntS, bns, bnq);
  k_bin<<<NAB, 256, 0, stream>>>(src, dst, gcntD, gcntS, pairD, keyS);
  k_boff<<<1, 64, 0, stream>>>(gcntD, bOffD);
  k_bucket_dst<<<NBUK, 256, 0, stream>>>(pairD, gcntD, bOffD, degi, nd, rowp, csr);
  k_bucket_src<<<NBUK, 256, 0, stream>>>(keyS, gcntS, ns);

  // features * ns -> bf16
  k_cvt<<<(NN*32 + 255)/256, 256, 0, stream>>>(features, ns, X);

  int sblk = (NN + 3)/4;             // 1 wave per node
  int gblk = (NN + 127)/128;         // GEMM row blocks

  // layer 0
  k_spmm8<128><<<sblk, 256, 0, stream>>>(X, rowp, degi, csr, nd, Y);
  k_gemm_mfma<0><<<dim3(1,gblk), 256, 0, stream>>>(Y, wt0, b0, ns, X, nullptr, nullptr, nullptr, NN, 128, 128);
  // layer 1
  k_spmm8<128><<<sblk, 256, 0, stream>>>(X, rowp, degi, csr, nd, Y);
  k_gemm_mfma<0><<<dim3(2,gblk), 256, 0, stream>>>(Y, wt1, b1, ns, X, nullptr, nullptr, nullptr, NN, 128, 256);
  // layer 2
  k_spmm8<256><<<sblk, 256, 0, stream>>>(X, rowp, degi, csr, nd, Y);
  k_gemm_mfma<1><<<dim3(2,gblk), 256, 0, stream>>>(Y, wt2, b2, nullptr, X, nullptr, nullptr, nullptr, NN, 256, 256);
  // MLP hidden: z = relu(h3 @ Wm1 + bm1) + fused BN column stats
  k_gemm_mfma<2><<<dim3(2,gblk), 256, 0, stream>>>(X, wtm1, bm1, nullptr, nullptr, z, bns, bnq, NN, 256, 200);

  // batchnorm finalize + final linear
  k_bn2<<<1, 256, 0, stream>>>(bns, bnq, gamma, beta, Wm2, bm2, w2a, cc2);
  k_final<<<sblk, 256, 0, stream>>>(z, w2a, cc2, out);
}